// Round 5
// baseline (275.045 us; speedup 1.0000x reference)
//
#include <hip/hip_runtime.h>

// ---------------------------------------------------------------------------
// Soft decision tree forward (all-f16 pipeline):
//   d = sigmoid(X @ T^T); leaf probs = depth-10 path products;
//   out = softmax(probs @ L)
//
// GEMM1/GEMM2: 256x256-tile, BK=64, 8-wave, 4-phase/K-tile pipelined core.
// Round-5 schedule: balanced LDS reads (8/4/8/4 per phase), b01 fragments of
// tile t+1 read at end of t's P4 behind counted vm-gates (8 then 4; never 0
// in steady state), carried in registers across the tile boundary. T2 row-XOR
// swizzle (0 conflicts, verified), setprio around MFMA, bijective XCD swizzle.
// ---------------------------------------------------------------------------

typedef unsigned short u16;
typedef _Float16 f16;
typedef _Float16 f16x8 __attribute__((ext_vector_type(8)));
typedef float f32x4 __attribute__((ext_vector_type(4)));

#define BATCH 32768
#define DIM   1024
#define NPAD  1024

#define WAIT_VM(N) asm volatile("s_waitcnt vmcnt(" #N ")" ::: "memory")
#define BARRIER()  asm volatile("s_barrier" ::: "memory")

// ---- f16 helpers ----
__device__ __forceinline__ u16 f2h(float f) {
    union { f16 h; u16 u; } v; v.h = (f16)f; return v.u;
}
__device__ __forceinline__ float h2f(u16 u) {
    union { u16 u; f16 h; } v; v.u = u; return (float)v.h;
}

// ---- async global->LDS, 16B/lane (dest = wave-uniform base + lane*16) ----
__device__ __forceinline__ void gl16(const u16* g, char* l) {
    __builtin_amdgcn_global_load_lds(
        (const __attribute__((address_space(1))) unsigned int*)g,
        (__attribute__((address_space(3))) unsigned int*)l, 16, 0, 0);
}

#define MFMA16(a, b, c) __builtin_amdgcn_mfma_f32_16x16x32_f16(a, b, c, 0, 0, 0)

// ---------------------------------------------------------------------------
// prep kernels (unchanged)
// ---------------------------------------------------------------------------
__global__ __launch_bounds__(256) void prep_x(const float4* __restrict__ x4,
                                              u16* __restrict__ xh, int n4) {
    int stride = gridDim.x * blockDim.x;
    for (int i = blockIdx.x * blockDim.x + threadIdx.x; i < n4; i += stride) {
        float4 v = x4[i];
        *(ushort4*)&xh[(size_t)i * 4] =
            make_ushort4(f2h(v.x), f2h(v.y), f2h(v.z), f2h(v.w));
    }
}

__global__ __launch_bounds__(256) void prep_t(const float* __restrict__ t,
                                              u16* __restrict__ th) {
    int i = blockIdx.x * 256 + threadIdx.x;
    int node = i >> 10;
    float v = (node < 1023) ? t[i] : 0.0f;
    th[i] = f2h(v);
}

__global__ __launch_bounds__(256) void prep_lt(const float* __restrict__ L,
                                               u16* __restrict__ LT) {
    __shared__ float tile[32][33];
    int bx = blockIdx.x, by = blockIdx.y;
    int tx = threadIdx.x & 31, ty = threadIdx.x >> 5;
#pragma unroll
    for (int r = 0; r < 4; r++)
        tile[ty + 8 * r][tx] = L[(size_t)(by * 32 + ty + 8 * r) * 1024 + bx * 32 + tx];
    __syncthreads();
#pragma unroll
    for (int r = 0; r < 4; r++)
        LT[(size_t)(bx * 32 + ty + 8 * r) * 1024 + by * 32 + tx] =
            f2h(tile[tx][ty + 8 * r]);
}

// bijective XCD swizzle: 512 blocks, 64 per XCD.
__device__ __forceinline__ void block_map(int bid, int& rb, int& cb) {
    int lid = (bid & 7) * 64 + (bid >> 3);
    rb = (lid >> 2) << 8;
    cb = (lid & 3) << 8;
}

// ---------------------------------------------------------------------------
// 4-phase/K-tile 256x256 GEMM core. A,B row-major [rows][1024] f16, K=NT*64.
// Wave (wm = wid>>2, wn = wid&3): rows wm*128+[0,128), cols wn*64+[0,64).
// LDS 128KiB: A dbuf [0,64K) (slot = kt&1, 32KB = 2 halves of 128 rows);
// B dbuf [64K,128K). Half = [128 rows][64 f16], row-XOR swizzle (row&7)<<4.
// Phase reads: P1 a0-3(8) | P2 b23(4) | P3 a4-7(8) | P4 b01(t+1)(4).
// Stages: P1 A-lo(t+1) | P2 A-hi(t+1) | P3 B-lo(t+2) | P4 B-hi(t+2).
// Gates (P4 tail): vm8 (B(t+1) landed, before b01 read), vm4 (A(t+1) landed).
// ---------------------------------------------------------------------------
template <int NT>
__device__ __forceinline__ void gemm_core8(const u16* __restrict__ Ap,
                                           const u16* __restrict__ Bp,
                                           int rb, int cb, char* lds,
                                           f32x4 acc[8][4])
{
    const int t = threadIdx.x, wid = t >> 6, lane = t & 63;
    const int wm = wid >> 2, wn = wid & 3;
    const int mr = lane & 15, kg = lane >> 4;

    // staging source (pre-swizzled so linear LDS dest + XOR'd read match)
    const int tr = t >> 3;
    const unsigned koff = 8u * ((unsigned)((t & 7) ^ (tr & 7)));
    const unsigned sAlo = (unsigned)(rb + tr) * 1024u + koff;
    const unsigned sAhi = sAlo + 131072u;
    const unsigned sBlo = (unsigned)(cb + tr) * 1024u + koff;
    const unsigned sBhi = sBlo + 131072u;

    // swizzled ds_read offsets
    const unsigned key = (unsigned)(mr & 7) << 4;
    const unsigned e0 = (unsigned)mr * 128u + (((unsigned)kg * 16u) ^ key);
    const unsigned e1 = (unsigned)mr * 128u + ((64u + (unsigned)kg * 16u) ^ key);
    const unsigned bbase = (unsigned)(wn & 1) * 8192u;
    const unsigned bhalf = (unsigned)(wn >> 1) * 16384u;

#pragma unroll
    for (int m = 0; m < 8; ++m)
#pragma unroll
        for (int n = 0; n < 4; ++n) acc[m][n] = (f32x4){0.f, 0.f, 0.f, 0.f};

    // stage one 128-row half (2 x gl16)
    auto stg = [&](int kt, unsigned srcb, const u16* G, int region, int halfo) {
        char* dst = lds + region + (kt & 1) * 32768 + halfo + t * 16;
        const u16* g = G + srcb + (unsigned)kt * 64u;
        gl16(g, dst);
        gl16(g + 65536, dst + 8192);
    };

    // prologue: tiles 0 and 1 fully staged (16 loads); wait A0+B0 (oldest 8)
    stg(0, sAlo, Ap, 0, 0);      stg(0, sAhi, Ap, 0, 16384);
    stg(0, sBlo, Bp, 65536, 0);  stg(0, sBhi, Bp, 65536, 16384);
    stg(1, sAlo, Ap, 0, 0);      stg(1, sAhi, Ap, 0, 16384);
    stg(1, sBlo, Bp, 65536, 0);  stg(1, sBhi, Bp, 65536, 16384);
    WAIT_VM(8);
    BARRIER();

    f16x8 a[4][2], b01[2][2], b23[2][2];

    // pre-read b01(0)
    {
        char* LB = lds + 65536 + bhalf;
#pragma unroll
        for (int n = 0; n < 2; ++n) {
            b01[n][0] = *(const f16x8*)(LB + bbase + n * 2048 + e0);
            b01[n][1] = *(const f16x8*)(LB + bbase + n * 2048 + e1);
        }
    }

#pragma unroll 1
    for (int kt = 0; kt < NT; ++kt) {
        char* LA = lds + (kt & 1) * 32768 + wm * 16384;
        char* LB = lds + 65536 + (kt & 1) * 32768 + bhalf;

        // ---------------- P1: read a0-3; stage A-lo(t+1); MFMA m0-3 x b01 ---
#pragma unroll
        for (int i = 0; i < 4; ++i) {
            a[i][0] = *(const f16x8*)(LA + i * 2048 + e0);
            a[i][1] = *(const f16x8*)(LA + i * 2048 + e1);
        }
        if (kt + 1 < NT) stg(kt + 1, sAlo, Ap, 0, 0);
        BARRIER();
        __builtin_amdgcn_s_setprio(1);
#pragma unroll
        for (int i = 0; i < 4; ++i)
#pragma unroll
            for (int n = 0; n < 2; ++n) {
                acc[i][n] = MFMA16(a[i][0], b01[n][0], acc[i][n]);
                acc[i][n] = MFMA16(a[i][1], b01[n][1], acc[i][n]);
            }
        __builtin_amdgcn_s_setprio(0);
        BARRIER();

        // ---------------- P2: read b23; stage A-hi(t+1); MFMA m0-3 x b23 ----
#pragma unroll
        for (int n = 0; n < 2; ++n) {
            b23[n][0] = *(const f16x8*)(LB + bbase + (2 + n) * 2048 + e0);
            b23[n][1] = *(const f16x8*)(LB + bbase + (2 + n) * 2048 + e1);
        }
        if (kt + 1 < NT) stg(kt + 1, sAhi, Ap, 0, 16384);
        BARRIER();
        __builtin_amdgcn_s_setprio(1);
#pragma unroll
        for (int i = 0; i < 4; ++i)
#pragma unroll
            for (int n = 0; n < 2; ++n) {
                acc[i][2 + n] = MFMA16(a[i][0], b23[n][0], acc[i][2 + n]);
                acc[i][2 + n] = MFMA16(a[i][1], b23[n][1], acc[i][2 + n]);
            }
        __builtin_amdgcn_s_setprio(0);
        BARRIER();

        // ---------------- P3: read a4-7; stage B-lo(t+2); MFMA m4-7 x b23 ---
#pragma unroll
        for (int i = 0; i < 4; ++i) {
            a[i][0] = *(const f16x8*)(LA + (4 + i) * 2048 + e0);
            a[i][1] = *(const f16x8*)(LA + (4 + i) * 2048 + e1);
        }
        if (kt + 2 < NT) stg(kt + 2, sBlo, Bp, 65536, 0);
        BARRIER();
        __builtin_amdgcn_s_setprio(1);
#pragma unroll
        for (int i = 0; i < 4; ++i)
#pragma unroll
            for (int n = 0; n < 2; ++n) {
                acc[4 + i][2 + n] = MFMA16(a[i][0], b23[n][0], acc[4 + i][2 + n]);
                acc[4 + i][2 + n] = MFMA16(a[i][1], b23[n][1], acc[4 + i][2 + n]);
            }
        __builtin_amdgcn_s_setprio(0);
        BARRIER();

        // ---------------- P4: stage B-hi(t+2); MFMA m4-7 x b01;
        //                  gate vm8; read b01(t+1); gate vm4 ----------------
        if (kt + 2 < NT) stg(kt + 2, sBhi, Bp, 65536, 16384);
        BARRIER();
        __builtin_amdgcn_s_setprio(1);
#pragma unroll
        for (int i = 0; i < 4; ++i)
#pragma unroll
            for (int n = 0; n < 2; ++n) {
                acc[4 + i][n] = MFMA16(a[i][0], b01[n][0], acc[4 + i][n]);
                acc[4 + i][n] = MFMA16(a[i][1], b01[n][1], acc[4 + i][n]);
            }
        __builtin_amdgcn_s_setprio(0);
        if (kt + 1 < NT) {
            // ensure B(t+1) landed (drain everything older than A(t+1)+B(t+2))
            if (kt + 2 < NT) { WAIT_VM(8); } else { WAIT_VM(4); }
            char* LB2 = lds + 65536 + ((kt + 1) & 1) * 32768 + bhalf;
#pragma unroll
            for (int n = 0; n < 2; ++n) {
                b01[n][0] = *(const f16x8*)(LB2 + bbase + n * 2048 + e0);
                b01[n][1] = *(const f16x8*)(LB2 + bbase + n * 2048 + e1);
            }
            // ensure A(t+1) landed before next P1 (leave B(t+2) in flight)
            if (kt + 2 < NT) { WAIT_VM(4); } else { WAIT_VM(0); }
        }
        BARRIER();
    }
}

// ---------------------------------------------------------------------------
// GEMM1: d = sigmoid(X @ T^T), store {d, 1-d} f16 pairs
// ---------------------------------------------------------------------------
__global__ __launch_bounds__(512, 2) void gemm1_8p(
    const u16* __restrict__ Xh, const u16* __restrict__ Th,
    ushort2* __restrict__ dpair)
{
    __shared__ __align__(16) char lds[131072];
    int rb, cb;
    block_map(blockIdx.x, rb, cb);
    f32x4 acc[8][4];
    gemm_core8<16>(Xh, Th, rb, cb, lds, acc);

    const int lane = threadIdx.x & 63, wid = threadIdx.x >> 6;
    const int wm = wid >> 2, wn = wid & 3;
    const int mr = lane & 15, fq = (lane >> 4) * 4;
#pragma unroll
    for (int m = 0; m < 8; ++m)
#pragma unroll
        for (int j = 0; j < 4; ++j) {
            int grow = rb + wm * 128 + m * 16 + fq + j;
#pragma unroll
            for (int n = 0; n < 4; ++n) {
                int gcol = cb + wn * 64 + n * 16 + mr;
                float s = acc[m][n][j];
                float d = 1.0f / (1.0f + __expf(-s));
                dpair[(size_t)grow * NPAD + gcol] = make_ushort2(f2h(d), f2h(1.0f - d));
            }
        }
}

// ---------------------------------------------------------------------------
// GEMM2: logits = probs @ LT^T -> d_out (f32)
// ---------------------------------------------------------------------------
__global__ __launch_bounds__(512, 2) void gemm2_8p(
    const u16* __restrict__ P, const u16* __restrict__ LT,
    float* __restrict__ out)
{
    __shared__ __align__(16) char lds[131072];
    int rb, cb;
    block_map(blockIdx.x, rb, cb);
    f32x4 acc[8][4];
    gemm_core8<16>(P, LT, rb, cb, lds, acc);

    const int lane = threadIdx.x & 63, wid = threadIdx.x >> 6;
    const int wm = wid >> 2, wn = wid & 3;
    const int mr = lane & 15, fq = (lane >> 4) * 4;
#pragma unroll
    for (int m = 0; m < 8; ++m)
#pragma unroll
        for (int j = 0; j < 4; ++j) {
            int grow = rb + wm * 128 + m * 16 + fq + j;
#pragma unroll
            for (int n = 0; n < 4; ++n) {
                int gcol = cb + wn * 64 + n * 16 + mr;
                out[(size_t)grow * 1024 + gcol] = acc[m][n][j];
            }
        }
}

// ---------------------------------------------------------------------------
// tree expansion: one wave per row; lane l owns leaves l*16 .. l*16+15
// ---------------------------------------------------------------------------
__global__ __launch_bounds__(256) void probs_kernel(const ushort2* __restrict__ dpair,
                                                    u16* __restrict__ probs) {
    const int t = threadIdx.x, w = t >> 6, l = t & 63;
    const int row = (blockIdx.x << 2) + w;
    const ushort2* dp = dpair + (size_t)row * NPAD;

    float prod = 1.0f;
#pragma unroll
    for (int lev = 0; lev < 6; lev++) {
        int node = (1 << lev) - 1 + (l >> (6 - lev));
        int bit  = (l >> (5 - lev)) & 1;
        ushort2 v = dp[node];
        prod *= h2f(bit ? v.y : v.x);
    }
    ushort2 n6 = dp[63 + l];
    ushort2 n7[2], n8[4], n9[8];
#pragma unroll
    for (int j = 0; j < 2; j++) n7[j] = dp[127 + 2 * l + j];
#pragma unroll
    for (int j = 0; j < 4; j++) n8[j] = dp[255 + 4 * l + j];
#pragma unroll
    for (int j = 0; j < 8; j++) n9[j] = dp[511 + 8 * l + j];

    u16 outv[16];
#pragma unroll
    for (int j = 0; j < 16; j++) {
        float f6 = h2f((j >> 3) ? n6.y : n6.x);
        ushort2 v7 = n7[j >> 3];       float f7 = h2f(((j >> 2) & 1) ? v7.y : v7.x);
        ushort2 v8 = n8[j >> 2];       float f8 = h2f(((j >> 1) & 1) ? v8.y : v8.x);
        ushort2 v9 = n9[j >> 1];       float f9 = h2f((j & 1) ? v9.y : v9.x);
        outv[j] = f2h(prod * f6 * f7 * f8 * f9);
    }
    ushort4* po = (ushort4*)(probs + (size_t)row * 1024 + (l << 4));
#pragma unroll
    for (int q = 0; q < 4; q++)
        po[q] = make_ushort4(outv[4 * q], outv[4 * q + 1], outv[4 * q + 2], outv[4 * q + 3]);
}

// ---------------------------------------------------------------------------
// row softmax in-place on d_out
// ---------------------------------------------------------------------------
__global__ __launch_bounds__(256) void softmax_kernel(float* __restrict__ out) {
    __shared__ float red[8];
    const int t = threadIdx.x, w = t >> 6, l = t & 63;
    float4* o4 = (float4*)out;
    const size_t base = (size_t)blockIdx.x * 256;
    float4 v = o4[base + t];

    float m = fmaxf(fmaxf(v.x, v.y), fmaxf(v.z, v.w));
#pragma unroll
    for (int off = 32; off; off >>= 1) m = fmaxf(m, __shfl_xor(m, off));
    if (l == 0) red[w] = m;
    __syncthreads();
    m = fmaxf(fmaxf(red[0], red[1]), fmaxf(red[2], red[3]));

    float e0 = __expf(v.x - m), e1 = __expf(v.y - m);
    float e2 = __expf(v.z - m), e3 = __expf(v.w - m);
    float s = e0 + e1 + e2 + e3;
#pragma unroll
    for (int off = 32; off; off >>= 1) s += __shfl_xor(s, off);
    if (l == 0) red[4 + w] = s;
    __syncthreads();
    s = red[4] + red[5] + red[6] + red[7];
    float inv = 1.0f / s;
    o4[base + t] = make_float4(e0 * inv, e1 * inv, e2 * inv, e3 * inv);
}

// ---------------------------------------------------------------------------
extern "C" void kernel_launch(void* const* d_in, const int* in_sizes, int n_in,
                              void* d_out, int out_size, void* d_ws, size_t ws_size,
                              hipStream_t stream) {
    const float* x  = (const float*)d_in[0];
    const float* ft = (const float*)d_in[1];
    const float* lp = (const float*)d_in[2];
    float* out = (float*)d_out;
    char* ws = (char*)d_ws;

    // ws layout: Xh 64Mi | Th 2Mi | LT 2Mi | dpair 128Mi | probs 64Mi
    u16* Xh = (u16*)ws;
    u16* Th = (u16*)(ws + (size_t)67108864);
    u16* LT = Th + (size_t)NPAD * DIM;
    ushort2* dpair = (ushort2*)(ws + (size_t)67108864 + 2 * 2097152);
    u16* probs = (u16*)(ws + (size_t)67108864 + 2 * 2097152 + (size_t)BATCH * NPAD * 4);

    prep_x<<<4096, 256, 0, stream>>>((const float4*)x, Xh, BATCH * DIM / 4);
    prep_t<<<4096, 256, 0, stream>>>(ft, Th);
    prep_lt<<<dim3(32, 32), 256, 0, stream>>>(lp, LT);
    gemm1_8p<<<512, 512, 0, stream>>>(Xh, Th, dpair);
    probs_kernel<<<8192, 256, 0, stream>>>(dpair, probs);
    gemm2_8p<<<512, 512, 0, stream>>>(probs, LT, out);
    softmax_kernel<<<32768, 256, 0, stream>>>(out);
}

// Round 6
// 260.663 us; speedup vs baseline: 1.0552x; 1.0552x over previous
//
#include <hip/hip_runtime.h>

// ---------------------------------------------------------------------------
// Soft decision tree forward (all-f16 pipeline), round 6: traffic surgery.
//   d = sigmoid(X @ T^T); leaf probs = depth-10 path products;
//   out = softmax(probs @ L)
//
// Changes vs round 5 (whose GEMM1 K-loop is kept frozen):
//  - d stored as f16 scalar (64 MiB) instead of {d,1-d} pair (128 MiB);
//    probs computes 1-d in f32.
//  - gemm2+softmax FUSED: 64-row x 1024-col blocks own complete rows ->
//    in-register softmax, final f32 written once. Deletes the 128 MiB logits
//    round-trip and the softmax kernel's 256 MiB traffic.
// ---------------------------------------------------------------------------

typedef unsigned short u16;
typedef _Float16 f16;
typedef _Float16 f16x8 __attribute__((ext_vector_type(8)));
typedef float f32x4 __attribute__((ext_vector_type(4)));

#define BATCH 32768
#define DIM   1024
#define NPAD  1024

#define WAIT_VM(N) asm volatile("s_waitcnt vmcnt(" #N ")" ::: "memory")
#define BARRIER()  asm volatile("s_barrier" ::: "memory")

// ---- f16 helpers ----
__device__ __forceinline__ u16 f2h(float f) {
    union { f16 h; u16 u; } v; v.h = (f16)f; return v.u;
}
__device__ __forceinline__ float h2f(u16 u) {
    union { u16 u; f16 h; } v; v.u = u; return (float)v.h;
}

// ---- async global->LDS (dest = wave-uniform base + lane*size) ----
__device__ __forceinline__ void gl16(const u16* g, char* l) {
    __builtin_amdgcn_global_load_lds(
        (const __attribute__((address_space(1))) unsigned int*)g,
        (__attribute__((address_space(3))) unsigned int*)l, 16, 0, 0);
}
__device__ __forceinline__ void gl4(const u16* g, char* l) {
    __builtin_amdgcn_global_load_lds(
        (const __attribute__((address_space(1))) unsigned int*)g,
        (__attribute__((address_space(3))) unsigned int*)l, 4, 0, 0);
}

#define MFMA16(a, b, c) __builtin_amdgcn_mfma_f32_16x16x32_f16(a, b, c, 0, 0, 0)

// ---------------------------------------------------------------------------
// prep kernels
// ---------------------------------------------------------------------------
__global__ __launch_bounds__(256) void prep_x(const float4* __restrict__ x4,
                                              u16* __restrict__ xh, int n4) {
    int stride = gridDim.x * blockDim.x;
    for (int i = blockIdx.x * blockDim.x + threadIdx.x; i < n4; i += stride) {
        float4 v = x4[i];
        *(ushort4*)&xh[(size_t)i * 4] =
            make_ushort4(f2h(v.x), f2h(v.y), f2h(v.z), f2h(v.w));
    }
}

__global__ __launch_bounds__(256) void prep_t(const float* __restrict__ t,
                                              u16* __restrict__ th) {
    int i = blockIdx.x * 256 + threadIdx.x;
    int node = i >> 10;
    float v = (node < 1023) ? t[i] : 0.0f;
    th[i] = f2h(v);
}

__global__ __launch_bounds__(256) void prep_lt(const float* __restrict__ L,
                                               u16* __restrict__ LT) {
    __shared__ float tile[32][33];
    int bx = blockIdx.x, by = blockIdx.y;
    int tx = threadIdx.x & 31, ty = threadIdx.x >> 5;
#pragma unroll
    for (int r = 0; r < 4; r++)
        tile[ty + 8 * r][tx] = L[(size_t)(by * 32 + ty + 8 * r) * 1024 + bx * 32 + tx];
    __syncthreads();
#pragma unroll
    for (int r = 0; r < 4; r++)
        LT[(size_t)(bx * 32 + ty + 8 * r) * 1024 + by * 32 + tx] =
            f2h(tile[tx][ty + 8 * r]);
}

// bijective XCD swizzle: 512 blocks, 64 per XCD.
__device__ __forceinline__ void block_map(int bid, int& rb, int& cb) {
    int lid = (bid & 7) * 64 + (bid >> 3);
    rb = (lid >> 2) << 8;
    cb = (lid & 3) << 8;
}

// ---------------------------------------------------------------------------
// GEMM1 core (round-5 4-phase 256x256 pipeline, frozen) — see prior rounds.
// ---------------------------------------------------------------------------
template <int NT>
__device__ __forceinline__ void gemm_core8(const u16* __restrict__ Ap,
                                           const u16* __restrict__ Bp,
                                           int rb, int cb, char* lds,
                                           f32x4 acc[8][4])
{
    const int t = threadIdx.x, wid = t >> 6, lane = t & 63;
    const int wm = wid >> 2, wn = wid & 3;
    const int mr = lane & 15, kg = lane >> 4;

    const int tr = t >> 3;
    const unsigned koff = 8u * ((unsigned)((t & 7) ^ (tr & 7)));
    const unsigned sAlo = (unsigned)(rb + tr) * 1024u + koff;
    const unsigned sAhi = sAlo + 131072u;
    const unsigned sBlo = (unsigned)(cb + tr) * 1024u + koff;
    const unsigned sBhi = sBlo + 131072u;

    const unsigned key = (unsigned)(mr & 7) << 4;
    const unsigned e0 = (unsigned)mr * 128u + (((unsigned)kg * 16u) ^ key);
    const unsigned e1 = (unsigned)mr * 128u + ((64u + (unsigned)kg * 16u) ^ key);
    const unsigned bbase = (unsigned)(wn & 1) * 8192u;
    const unsigned bhalf = (unsigned)(wn >> 1) * 16384u;

#pragma unroll
    for (int m = 0; m < 8; ++m)
#pragma unroll
        for (int n = 0; n < 4; ++n) acc[m][n] = (f32x4){0.f, 0.f, 0.f, 0.f};

    auto stg = [&](int kt, unsigned srcb, const u16* G, int region, int halfo) {
        char* dst = lds + region + (kt & 1) * 32768 + halfo + t * 16;
        const u16* g = G + srcb + (unsigned)kt * 64u;
        gl16(g, dst);
        gl16(g + 65536, dst + 8192);
    };

    stg(0, sAlo, Ap, 0, 0);      stg(0, sAhi, Ap, 0, 16384);
    stg(0, sBlo, Bp, 65536, 0);  stg(0, sBhi, Bp, 65536, 16384);
    stg(1, sAlo, Ap, 0, 0);      stg(1, sAhi, Ap, 0, 16384);
    stg(1, sBlo, Bp, 65536, 0);  stg(1, sBhi, Bp, 65536, 16384);
    WAIT_VM(8);
    BARRIER();

    f16x8 a[4][2], b01[2][2], b23[2][2];

    {
        char* LB = lds + 65536 + bhalf;
#pragma unroll
        for (int n = 0; n < 2; ++n) {
            b01[n][0] = *(const f16x8*)(LB + bbase + n * 2048 + e0);
            b01[n][1] = *(const f16x8*)(LB + bbase + n * 2048 + e1);
        }
    }

#pragma unroll 1
    for (int kt = 0; kt < NT; ++kt) {
        char* LA = lds + (kt & 1) * 32768 + wm * 16384;
        char* LB = lds + 65536 + (kt & 1) * 32768 + bhalf;

        // P1: read a0-3; stage A-lo(t+1); MFMA m0-3 x b01
#pragma unroll
        for (int i = 0; i < 4; ++i) {
            a[i][0] = *(const f16x8*)(LA + i * 2048 + e0);
            a[i][1] = *(const f16x8*)(LA + i * 2048 + e1);
        }
        if (kt + 1 < NT) stg(kt + 1, sAlo, Ap, 0, 0);
        BARRIER();
        __builtin_amdgcn_s_setprio(1);
#pragma unroll
        for (int i = 0; i < 4; ++i)
#pragma unroll
            for (int n = 0; n < 2; ++n) {
                acc[i][n] = MFMA16(a[i][0], b01[n][0], acc[i][n]);
                acc[i][n] = MFMA16(a[i][1], b01[n][1], acc[i][n]);
            }
        __builtin_amdgcn_s_setprio(0);
        BARRIER();

        // P2: read b23; stage A-hi(t+1); MFMA m0-3 x b23
#pragma unroll
        for (int n = 0; n < 2; ++n) {
            b23[n][0] = *(const f16x8*)(LB + bbase + (2 + n) * 2048 + e0);
            b23[n][1] = *(const f16x8*)(LB + bbase + (2 + n) * 2048 + e1);
        }
        if (kt + 1 < NT) stg(kt + 1, sAhi, Ap, 0, 16384);
        BARRIER();
        __builtin_amdgcn_s_setprio(1);
#pragma unroll
        for (int i = 0; i < 4; ++i)
#pragma unroll
            for (int n = 0; n < 2; ++n) {
                acc[i][2 + n] = MFMA16(a[i][0], b23[n][0], acc[i][2 + n]);
                acc[i][2 + n] = MFMA16(a[i][1], b23[n][1], acc[i][2 + n]);
            }
        __builtin_amdgcn_s_setprio(0);
        BARRIER();

        // P3: read a4-7; stage B-lo(t+2); MFMA m4-7 x b23
#pragma unroll
        for (int i = 0; i < 4; ++i) {
            a[i][0] = *(const f16x8*)(LA + (4 + i) * 2048 + e0);
            a[i][1] = *(const f16x8*)(LA + (4 + i) * 2048 + e1);
        }
        if (kt + 2 < NT) stg(kt + 2, sBlo, Bp, 65536, 0);
        BARRIER();
        __builtin_amdgcn_s_setprio(1);
#pragma unroll
        for (int i = 0; i < 4; ++i)
#pragma unroll
            for (int n = 0; n < 2; ++n) {
                acc[4 + i][2 + n] = MFMA16(a[i][0], b23[n][0], acc[4 + i][2 + n]);
                acc[4 + i][2 + n] = MFMA16(a[i][1], b23[n][1], acc[4 + i][2 + n]);
            }
        __builtin_amdgcn_s_setprio(0);
        BARRIER();

        // P4: stage B-hi(t+2); MFMA m4-7 x b01; gates; read b01(t+1)
        if (kt + 2 < NT) stg(kt + 2, sBhi, Bp, 65536, 16384);
        BARRIER();
        __builtin_amdgcn_s_setprio(1);
#pragma unroll
        for (int i = 0; i < 4; ++i)
#pragma unroll
            for (int n = 0; n < 2; ++n) {
                acc[4 + i][n] = MFMA16(a[i][0], b01[n][0], acc[4 + i][n]);
                acc[4 + i][n] = MFMA16(a[i][1], b01[n][1], acc[4 + i][n]);
            }
        __builtin_amdgcn_s_setprio(0);
        if (kt + 1 < NT) {
            if (kt + 2 < NT) { WAIT_VM(8); } else { WAIT_VM(4); }
            char* LB2 = lds + 65536 + ((kt + 1) & 1) * 32768 + bhalf;
#pragma unroll
            for (int n = 0; n < 2; ++n) {
                b01[n][0] = *(const f16x8*)(LB2 + bbase + n * 2048 + e0);
                b01[n][1] = *(const f16x8*)(LB2 + bbase + n * 2048 + e1);
            }
            if (kt + 2 < NT) { WAIT_VM(4); } else { WAIT_VM(0); }
        }
        BARRIER();
    }
}

// ---------------------------------------------------------------------------
// GEMM1: d = sigmoid(X @ T^T), store d f16 (scalar)
// ---------------------------------------------------------------------------
__global__ __launch_bounds__(512, 2) void gemm1_8p(
    const u16* __restrict__ Xh, const u16* __restrict__ Th,
    u16* __restrict__ dval)
{
    __shared__ __align__(16) char lds[131072];
    int rb, cb;
    block_map(blockIdx.x, rb, cb);
    f32x4 acc[8][4];
    gemm_core8<16>(Xh, Th, rb, cb, lds, acc);

    const int lane = threadIdx.x & 63, wid = threadIdx.x >> 6;
    const int wm = wid >> 2, wn = wid & 3;
    const int mr = lane & 15, fq = (lane >> 4) * 4;
#pragma unroll
    for (int m = 0; m < 8; ++m)
#pragma unroll
        for (int j = 0; j < 4; ++j) {
            int grow = rb + wm * 128 + m * 16 + fq + j;
#pragma unroll
            for (int n = 0; n < 4; ++n) {
                int gcol = cb + wn * 64 + n * 16 + mr;
                float s = acc[m][n][j];
                float d = 1.0f / (1.0f + __expf(-s));
                dval[(size_t)grow * NPAD + gcol] = f2h(d);
            }
        }
}

// ---------------------------------------------------------------------------
// tree expansion: one wave per row; lane l owns leaves l*16 .. l*16+15
// reads d f16; 1-d computed in f32
// ---------------------------------------------------------------------------
__global__ __launch_bounds__(256) void probs_kernel(const u16* __restrict__ dval,
                                                    u16* __restrict__ probs) {
    const int t = threadIdx.x, w = t >> 6, l = t & 63;
    const int row = (blockIdx.x << 2) + w;
    const u16* dp = dval + (size_t)row * NPAD;

    float prod = 1.0f;
#pragma unroll
    for (int lev = 0; lev < 6; lev++) {
        int node = (1 << lev) - 1 + (l >> (6 - lev));
        int bit  = (l >> (5 - lev)) & 1;
        float v = h2f(dp[node]);
        prod *= bit ? (1.0f - v) : v;
    }
    float d6 = h2f(dp[63 + l]);
    float d7[2], d8[4], d9[8];
#pragma unroll
    for (int j = 0; j < 2; j++) d7[j] = h2f(dp[127 + 2 * l + j]);
#pragma unroll
    for (int j = 0; j < 4; j++) d8[j] = h2f(dp[255 + 4 * l + j]);
#pragma unroll
    for (int j = 0; j < 8; j++) d9[j] = h2f(dp[511 + 8 * l + j]);

    u16 outv[16];
#pragma unroll
    for (int j = 0; j < 16; j++) {
        float f6 = (j >> 3) ? (1.0f - d6) : d6;
        float v7 = d7[j >> 3];  float f7 = ((j >> 2) & 1) ? (1.0f - v7) : v7;
        float v8 = d8[j >> 2];  float f8 = ((j >> 1) & 1) ? (1.0f - v8) : v8;
        float v9 = d9[j >> 1];  float f9 = (j & 1) ? (1.0f - v9) : v9;
        outv[j] = f2h(prod * f6 * f7 * f8 * f9);
    }
    ushort4* po = (ushort4*)(probs + (size_t)row * 1024 + (l << 4));
#pragma unroll
    for (int q = 0; q < 4; q++)
        po[q] = make_ushort4(outv[4 * q], outv[4 * q + 1], outv[4 * q + 2], outv[4 * q + 3]);
}

// ---------------------------------------------------------------------------
// FUSED GEMM2 + SOFTMAX: out = softmax(probs @ LT^T), one block = 64 full rows
// 8 waves; wave wn owns cols wn*128+[0,128): acc[4][8] (m-frag 16 rows, n-frag
// 16 cols). BK=32, 2-slot LDS dbuf: slot = B[1024][32] (64KB) + A[64][32](4KB),
// both row-XOR-swizzled (64B rows): 16B-slot ^= (row>>1)&3. B staged via gl16
// with pre-swizzled source; A staged via gl4 (uniform 2 loads/thread).
// Simple 2-phase schedule with __syncthreads (vm+lgkm drain semantics).
// ---------------------------------------------------------------------------
__global__ __launch_bounds__(512, 2) void gemm2sm(
    const u16* __restrict__ P, const u16* __restrict__ LT,
    float* __restrict__ out)
{
    __shared__ __align__(16) char lds[139264];   // 2 * (65536 B + 4096 A)
    const int t = threadIdx.x, wid = t >> 6, lane = t & 63;
    const int wn = wid;                     // wave owns cols wn*128
    const int mr = lane & 15, kg = lane >> 4;
    const int rb = blockIdx.x * 64;

    // ---- staging source offsets (pre-swizzled) ----
    // B: call c stages tile-row c*128 + (t>>2), 16B-slot t&3.
    const int brow_t = t >> 2;
    const unsigned bkoff = 8u * (unsigned)((t & 3) ^ ((t >> 3) & 3));
    // A (gl4): call c: row = wid*8 + c*4 + (lane>>4), byte-in-row = (lane&15)*4
    //   src slot = ((lane&15)>>2) ^ ((row>>1)&3); elem-in-slot = (lane&3)*2
    const int ar_base = wid * 8 + (lane >> 4);      // + c*4
    const int a_sl = (lane & 15) >> 2;
    const int a_el = (lane & 3) * 2;

    // ---- swizzled ds_read offsets ----
    unsigned offA[4], offB[8];
#pragma unroll
    for (int m = 0; m < 4; ++m) {
        int row = m * 16 + mr;
        offA[m] = (unsigned)(row * 64) + ((unsigned)(kg ^ ((row >> 1) & 3)) << 4);
    }
#pragma unroll
    for (int n = 0; n < 8; ++n) {
        int row = wn * 128 + n * 16 + mr;
        offB[n] = (unsigned)(row * 64) + ((unsigned)(kg ^ ((row >> 1) & 3)) << 4);
    }

    f32x4 acc[4][8];
#pragma unroll
    for (int m = 0; m < 4; ++m)
#pragma unroll
        for (int n = 0; n < 8; ++n) acc[m][n] = (f32x4){0.f, 0.f, 0.f, 0.f};

    auto stage = [&](int kt) {
        char* sb = lds + (kt & 1) * 69632;
        const u16* bsrc = LT + (size_t)brow_t * 1024 + (unsigned)kt * 32u + bkoff;
#pragma unroll
        for (int c = 0; c < 8; ++c)
            gl16(bsrc + c * 131072, sb + c * 8192 + t * 16);
        char* sa = sb + 65536 + wid * 512;
#pragma unroll
        for (int c = 0; c < 2; ++c) {
            int row = ar_base + c * 4;
            const u16* asrc = P + (size_t)(rb + row) * 1024 + (unsigned)kt * 32u
                              + (unsigned)((a_sl ^ ((row >> 1) & 3)) * 8 + a_el);
            gl4(asrc, sa + c * 256 + (lane & 63) * 4);
        }
    };

    stage(0);
    __syncthreads();

#pragma unroll 1
    for (int kt = 0; kt < 32; ++kt) {
        if (kt + 1 < 32) stage(kt + 1);
        char* sb = lds + (kt & 1) * 69632;
        char* sa = sb + 65536;
        f16x8 a[4], b[8];
#pragma unroll
        for (int m = 0; m < 4; ++m) a[m] = *(const f16x8*)(sa + offA[m]);
#pragma unroll
        for (int n = 0; n < 8; ++n) b[n] = *(const f16x8*)(sb + offB[n]);
        __builtin_amdgcn_s_setprio(1);
#pragma unroll
        for (int m = 0; m < 4; ++m)
#pragma unroll
            for (int n = 0; n < 8; ++n)
                acc[m][n] = MFMA16(a[m], b[n], acc[m][n]);
        __builtin_amdgcn_s_setprio(0);
        __syncthreads();   // drains vm (next slot staged) + lgkm; barrier
    }

    // ---------------- in-register softmax over full rows ----------------
    // thread rows: r(m,j) = m*16 + (lane>>4)*4 + j; cols: wn*128 + n*16 + mr
    float* red = (float*)lds;          // [64][8] max, then reuse +2048B for sum
    float* red2 = (float*)(lds + 2048);
    const int fq = (lane >> 4) * 4;

    float mx[4][4];
#pragma unroll
    for (int m = 0; m < 4; ++m)
#pragma unroll
        for (int j = 0; j < 4; ++j) {
            float v = acc[m][0][j];
#pragma unroll
            for (int n = 1; n < 8; ++n) v = fmaxf(v, acc[m][n][j]);
#pragma unroll
            for (int off = 1; off < 16; off <<= 1)
                v = fmaxf(v, __shfl_xor(v, off));
            mx[m][j] = v;
        }
    if ((lane & 15) == 0) {
#pragma unroll
        for (int m = 0; m < 4; ++m)
#pragma unroll
            for (int j = 0; j < 4; ++j)
                red[(m * 16 + fq + j) * 8 + wid] = mx[m][j];
    }
    __syncthreads();
    if (t < 64) {
        float v = red[t * 8];
#pragma unroll
        for (int w = 1; w < 8; ++w) v = fmaxf(v, red[t * 8 + w]);
        red[t * 8] = v;
    }
    __syncthreads();

    float sm[4][4];
#pragma unroll
    for (int m = 0; m < 4; ++m)
#pragma unroll
        for (int j = 0; j < 4; ++j) {
            float M = red[(m * 16 + fq + j) * 8];
            float s = 0.f;
#pragma unroll
            for (int n = 0; n < 8; ++n) {
                float e = __expf(acc[m][n][j] - M);
                acc[m][n][j] = e;
                s += e;
            }
#pragma unroll
            for (int off = 1; off < 16; off <<= 1)
                s += __shfl_xor(s, off);
            sm[m][j] = s;
        }
    if ((lane & 15) == 0) {
#pragma unroll
        for (int m = 0; m < 4; ++m)
#pragma unroll
            for (int j = 0; j < 4; ++j)
                red2[(m * 16 + fq + j) * 8 + wid] = sm[m][j];
    }
    __syncthreads();
    if (t < 64) {
        float v = 0.f;
#pragma unroll
        for (int w = 0; w < 8; ++w) v += red2[t * 8 + w];
        red2[t * 8] = 1.0f / v;
    }
    __syncthreads();

#pragma unroll
    for (int m = 0; m < 4; ++m)
#pragma unroll
        for (int j = 0; j < 4; ++j) {
            int grow = rb + m * 16 + fq + j;
            float inv = red2[(m * 16 + fq + j) * 8];
#pragma unroll
            for (int n = 0; n < 8; ++n) {
                int gcol = wn * 128 + n * 16 + mr;
                out[(size_t)grow * 1024 + gcol] = acc[m][n][j] * inv;
            }
        }
}

// ---------------------------------------------------------------------------
extern "C" void kernel_launch(void* const* d_in, const int* in_sizes, int n_in,
                              void* d_out, int out_size, void* d_ws, size_t ws_size,
                              hipStream_t stream) {
    const float* x  = (const float*)d_in[0];
    const float* ft = (const float*)d_in[1];
    const float* lp = (const float*)d_in[2];
    float* out = (float*)d_out;
    char* ws = (char*)d_ws;

    // ws layout: Xh 64Mi | Th 2Mi | LT 2Mi | dval 64Mi | probs 64Mi
    u16* Xh = (u16*)ws;
    u16* Th = (u16*)(ws + (size_t)67108864);
    u16* LT = Th + (size_t)NPAD * DIM;
    u16* dval = (u16*)(ws + (size_t)67108864 + 2 * 2097152);
    u16* probs = dval + (size_t)BATCH * NPAD;

    prep_x<<<4096, 256, 0, stream>>>((const float4*)x, Xh, BATCH * DIM / 4);
    prep_t<<<4096, 256, 0, stream>>>(ft, Th);
    prep_lt<<<dim3(32, 32), 256, 0, stream>>>(lp, LT);
    gemm1_8p<<<512, 512, 0, stream>>>(Xh, Th, dval);
    probs_kernel<<<8192, 256, 0, stream>>>(dval, probs);
    gemm2sm<<<512, 512, 0, stream>>>(probs, LT, out);
}